// Round 3
// baseline (516.495 us; speedup 1.0000x reference)
//
#include <hip/hip_runtime.h>
#include <math.h>

#define NEG 0.2f

// ---------------------------------------------------------------------------
// CSR build: fused histogram -> single-block scan -> fused scatter
// ---------------------------------------------------------------------------
__global__ void k_hist(const int* __restrict__ dst_s, int Es,
                       const int* __restrict__ dst_n, int En,
                       int* __restrict__ deg_s, int* __restrict__ deg_n) {
    int i = blockIdx.x * 256 + threadIdx.x;
    if (i < Es) atomicAdd(&deg_s[dst_s[i]], 1);
    int j = i - Es;
    if (j >= 0 && j < En) atomicAdd(&deg_n[dst_n[j]], 1);
}

__global__ __launch_bounds__(1024) void k_scan2(int* a, int na, int* b, int nb) {
    int* p = (blockIdx.x == 0) ? a : b;
    int n  = (blockIdx.x == 0) ? na : nb;
    __shared__ int sums[1024];
    int t = threadIdx.x;
    int C = (n + 1023) >> 10;
    int base = t * C;
    int s = 0;
    for (int j = 0; j < C; ++j) { int i = base + j; if (i < n) s += p[i]; }
    sums[t] = s;
    __syncthreads();
    for (int off = 1; off < 1024; off <<= 1) {
        int v = (t >= off) ? sums[t - off] : 0;
        __syncthreads();
        sums[t] += v;
        __syncthreads();
    }
    int run = (t == 0) ? 0 : sums[t - 1];
    for (int j = 0; j < C; ++j) {
        int i = base + j;
        if (i < n) { int v = p[i]; p[i] = run; run += v; }
    }
}

__global__ void k_scatter(const int* __restrict__ src_s, const int* __restrict__ dst_s, int Es,
                          const int* __restrict__ src_n, const int* __restrict__ dst_n, int En,
                          int* __restrict__ cur_s, int* __restrict__ cur_n,
                          int* __restrict__ csr_s, int* __restrict__ csr_n) {
    int i = blockIdx.x * 256 + threadIdx.x;
    if (i < Es) {
        int pos = atomicAdd(&cur_s[dst_s[i]], 1);
        csr_s[pos] = src_s[i];
    }
    int j = i - Es;
    if (j >= 0 && j < En) {
        int pos = atomicAdd(&cur_n[dst_n[j]], 1);
        csr_n[pos] = src_n[j];
    }
}

// ---------------------------------------------------------------------------
// helpers
// ---------------------------------------------------------------------------
static __device__ __forceinline__ void fma4(float4& d, float s, const float4 w) {
    d.x = fmaf(s, w.x, d.x); d.y = fmaf(s, w.y, d.y);
    d.z = fmaf(s, w.z, d.z); d.w = fmaf(s, w.w, d.w);
}
static __device__ __forceinline__ float4 lrelu4(float4 a, float4 b) {
    float4 r; float v;
    v = a.x + b.x; r.x = (v > 0.f) ? v : NEG * v;
    v = a.y + b.y; r.y = (v > 0.f) ? v : NEG * v;
    v = a.z + b.z; r.z = (v > 0.f) ? v : NEG * v;
    v = a.w + b.w; r.w = (v > 0.f) ? v : NEG * v;
    return r;
}

// Sum across each 16-lane DPP row (head = lanes 16h..16h+15) in ~4 VALU-DPP
// adds instead of 4 ds-pipe shuffles (~16 cyc vs ~140 cyc serial chain).
#define DPP_ADD(x, ctrl) \
    ((x) + __int_as_float(__builtin_amdgcn_update_dpp( \
        __float_as_int(x), __float_as_int(x), (ctrl), 0xF, 0xF, true)))
static __device__ __forceinline__ float rowsum16(float v) {
    v = DPP_ADD(v, 0xB1);   // quad_perm [1,0,3,2]  : pairs (xor 1)
    v = DPP_ADD(v, 0x4E);   // quad_perm [2,3,0,1]  : quads (xor 2)
    v = DPP_ADD(v, 0x141);  // row_half_mirror      : across quads in 8
    v = DPP_ADD(v, 0x140);  // row_mirror           : across halves in 16
    return v;
}

// ---------------------------------------------------------------------------
// GATv2, both layers in ONE persistent launch (blockIdx < split -> seen).
// One node per wave; lane owns dims d0=lane*4 (head h = lanes 16h..16h+15).
// LDS stages only Wd|Wr (32KB -> 4 blocks/CU with launch_bounds(256,4)).
// Ws/biases/attn live in per-wave registers (coalesced global loads, once).
// fs computed on the fly per edge; online softmax; DPP head-reduction.
// ---------------------------------------------------------------------------
__global__ __launch_bounds__(256, 4) void k_gat(
    const float* __restrict__ xsrc_s, const int* __restrict__ pfx_s, const int* __restrict__ csr_s,
    const float* __restrict__ Ws_s, const float* __restrict__ bs_s,
    const float* __restrict__ Wd_s, const float* __restrict__ bd_s,
    const float* __restrict__ at_s,
    const float* __restrict__ Wr_s, const float* __restrict__ br_s,
    const float* __restrict__ xsrc_n, const int* __restrict__ pfx_n, const int* __restrict__ csr_n,
    const float* __restrict__ Ws_n, const float* __restrict__ bs_n,
    const float* __restrict__ Wd_n, const float* __restrict__ bd_n,
    const float* __restrict__ at_n,
    const float* __restrict__ Wr_n, const float* __restrict__ br_n,
    const float* __restrict__ x_ag,
    float* __restrict__ xcat, int n_dst, int split)
{
    __shared__ __align__(16) float sWd[16 * 256];
    __shared__ __align__(16) float sWr[16 * 256];

    const bool seen = (int)blockIdx.x < split;
    const float* x_src = seen ? xsrc_s : xsrc_n;
    const int*   pfx   = seen ? pfx_s  : pfx_n;
    const int*   csr   = seen ? csr_s  : csr_n;
    const float* Ws    = seen ? Ws_s   : Ws_n;
    const float* bs    = seen ? bs_s   : bs_n;
    const float* Wd    = seen ? Wd_s   : Wd_n;
    const float* bd    = seen ? bd_s   : bd_n;
    const float* at    = seen ? at_s   : at_n;
    const float* Wr    = seen ? Wr_s   : Wr_n;
    const float* br    = seen ? br_s   : br_n;
    const int col = seen ? 0 : 256;
    const int b   = seen ? (int)blockIdx.x : (int)blockIdx.x - split;
    const int nb  = seen ? split : (int)gridDim.x - split;

    int t = threadIdx.x;
#pragma unroll
    for (int i = 0; i < 4; ++i)
        ((float4*)sWd)[t + i * 256] = ((const float4*)Wd)[t + i * 256];
#pragma unroll
    for (int i = 0; i < 4; ++i)
        ((float4*)sWr)[t + i * 256] = ((const float4*)Wr)[t + i * 256];
    __syncthreads();

    const int wave = t >> 6, lane = t & 63;
    const int d0 = lane * 4;

    // wave-lifetime constants (coalesced 1KB-row global loads, once)
    float4 ws_r[8];
#pragma unroll
    for (int k = 0; k < 8; ++k) ws_r[k] = *(const float4*)&Ws[k * 256 + d0];
    const float4 bsv = *(const float4*)&bs[d0];
    const float4 atv = *(const float4*)&at[d0];
    const float4 bdv = *(const float4*)&bd[d0];
    const float4 brv = *(const float4*)&br[d0];

    for (int node = b * 4 + wave; node < n_dst; node += nb * 4) {
        int end   = pfx[node];
        int start = node ? pfx[node - 1] : 0;
        int deg   = end - start;

        // fd = x_ag[node]@Wd + bd, fr = x_ag[node]@Wr + br (4 dims/lane)
        float4 fd = bdv, fr = brv;
        const float* xr = x_ag + (size_t)node * 16;
#pragma unroll
        for (int kq = 0; kq < 4; ++kq) {
            float4 xv = *(const float4*)&xr[kq * 4];
#pragma unroll
            for (int kk = 0; kk < 4; ++kk) {
                int k = kq * 4 + kk;
                float xk = (kk == 0) ? xv.x : (kk == 1) ? xv.y : (kk == 2) ? xv.z : xv.w;
                fma4(fd, xk, *(const float4*)&sWd[k * 256 + d0]);
                fma4(fr, xk, *(const float4*)&sWr[k * 256 + d0]);
            }
        }

        float m = -INFINITY, l = 0.f;
        float4 acc = make_float4(0.f, 0.f, 0.f, 0.f);

        // 2-deep software pipeline over this node's edges
        int s1 = (deg > 0) ? csr[start] : 0;
        int s2 = (deg > 1) ? csr[start + 1] : 0;
        float4 f0 = *(const float4*)&x_src[(size_t)s1 * 8];
        float4 f1 = *(const float4*)&x_src[(size_t)s1 * 8 + 4];
        for (int e = 0; e < deg; ++e) {
            float4 g0 = *(const float4*)&x_src[(size_t)s2 * 8];
            float4 g1 = *(const float4*)&x_src[(size_t)s2 * 8 + 4];
            int s3 = (e + 2 < deg) ? csr[start + e + 2] : 0;

            float4 fs = bsv;
            fma4(fs, f0.x, ws_r[0]);
            fma4(fs, f0.y, ws_r[1]);
            fma4(fs, f0.z, ws_r[2]);
            fma4(fs, f0.w, ws_r[3]);
            fma4(fs, f1.x, ws_r[4]);
            fma4(fs, f1.y, ws_r[5]);
            fma4(fs, f1.z, ws_r[6]);
            fma4(fs, f1.w, ws_r[7]);

            float4 tt = lrelu4(fs, fd);
            float sc = tt.x * atv.x;
            sc = fmaf(tt.y, atv.y, sc);
            sc = fmaf(tt.z, atv.z, sc);
            sc = fmaf(tt.w, atv.w, sc);
            sc = rowsum16(sc);          // all 16 lanes of the head get the sum

            float mn = fmaxf(m, sc);
            float corr = __expf(m - mn);      // 0 on first edge (m = -inf)
            float p = __expf(sc - mn);
            l = fmaf(l, corr, p);
            acc.x = fmaf(acc.x, corr, p * fs.x);
            acc.y = fmaf(acc.y, corr, p * fs.y);
            acc.z = fmaf(acc.z, corr, p * fs.z);
            acc.w = fmaf(acc.w, corr, p * fs.w);
            m = mn;

            f0 = g0; f1 = g1; s2 = s3;
        }

        float inv = (l > 0.f) ? 1.f / l : 0.f;   // zero in-degree -> rst = 0
        float4 o;
        o.x = fmaxf(fmaf(acc.x, inv, fr.x), 0.f);
        o.y = fmaxf(fmaf(acc.y, inv, fr.y), 0.f);
        o.z = fmaxf(fmaf(acc.z, inv, fr.z), 0.f);
        o.w = fmaxf(fmaf(acc.w, inv, fr.w), 0.f);
        *(float4*)&xcat[(size_t)node * 512 + col + d0] = o;
    }
}

// ---------------------------------------------------------------------------
// out = relu(X[M,512] @ W[512,256] + b). f32 vector GEMM, KT=32 LDS tiles.
// ---------------------------------------------------------------------------
#define KT 32
__global__ __launch_bounds__(256) void k_mlp(
    const float* __restrict__ X, const float* __restrict__ W,
    const float* __restrict__ b, float* __restrict__ out, int M)
{
    __shared__ __align__(16) float sW[KT * 256];   // 32 KB
    __shared__ __align__(16) float sX[16 * KT];    // 2 KB
    int t = threadIdx.x;
    int rbase = blockIdx.x * 16;
    int col_q = t & 63;
    int row_q = t >> 6;
    float acc[4][4] = {};

    for (int k0 = 0; k0 < 512; k0 += KT) {
        __syncthreads();
#pragma unroll
        for (int i = 0; i < 8; ++i) {
            int idx = t + i * 256;
            ((float4*)sW)[idx] = ((const float4*)(W + k0 * 256))[idx];
        }
        if (t < 128) {
            int r = t >> 3;
            int qq = t & 7;
            int row = rbase + r;
            float4 v = (row < M) ? *(const float4*)&X[(size_t)row * 512 + k0 + qq * 4]
                                 : make_float4(0.f, 0.f, 0.f, 0.f);
            *(float4*)&sX[r * KT + qq * 4] = v;
        }
        __syncthreads();
#pragma unroll 4
        for (int k = 0; k < KT; ++k) {
            float4 w = *(const float4*)&sW[k * 256 + col_q * 4];
#pragma unroll
            for (int r = 0; r < 4; ++r) {
                float x = sX[(row_q * 4 + r) * KT + k];
                acc[r][0] = fmaf(x, w.x, acc[r][0]);
                acc[r][1] = fmaf(x, w.y, acc[r][1]);
                acc[r][2] = fmaf(x, w.z, acc[r][2]);
                acc[r][3] = fmaf(x, w.w, acc[r][3]);
            }
        }
    }
    float4 bias = *(const float4*)&b[col_q * 4];
#pragma unroll
    for (int r = 0; r < 4; ++r) {
        int row = rbase + row_q * 4 + r;
        if (row < M) {
            float4 o;
            o.x = fmaxf(acc[r][0] + bias.x, 0.f);
            o.y = fmaxf(acc[r][1] + bias.y, 0.f);
            o.z = fmaxf(acc[r][2] + bias.z, 0.f);
            o.w = fmaxf(acc[r][3] + bias.w, 0.f);
            *(float4*)&out[(size_t)row * 256 + col_q * 4] = o;
        }
    }
}

// ---------------------------------------------------------------------------
extern "C" void kernel_launch(void* const* d_in, const int* in_sizes, int n_in,
                              void* d_out, int out_size, void* d_ws, size_t ws_size,
                              hipStream_t stream) {
    const float* x_gt   = (const float*)d_in[0];
    const float* x_ubs  = (const float*)d_in[1];
    const float* x_ag   = (const float*)d_in[2];
    const int* seen_src = (const int*)d_in[3];
    const int* seen_dst = (const int*)d_in[4];
    const int* near_src = (const int*)d_in[5];
    const int* near_dst = (const int*)d_in[6];
    const float* Ws_s = (const float*)d_in[7];  const float* bs_s = (const float*)d_in[8];
    const float* Wd_s = (const float*)d_in[9];  const float* bd_s = (const float*)d_in[10];
    const float* at_s = (const float*)d_in[11];
    const float* Wr_s = (const float*)d_in[12]; const float* br_s = (const float*)d_in[13];
    const float* Ws_n = (const float*)d_in[14]; const float* bs_n = (const float*)d_in[15];
    const float* Wd_n = (const float*)d_in[16]; const float* bd_n = (const float*)d_in[17];
    const float* at_n = (const float*)d_in[18];
    const float* Wr_n = (const float*)d_in[19]; const float* br_n = (const float*)d_in[20];
    const float* W_a  = (const float*)d_in[21]; const float* b_a  = (const float*)d_in[22];

    const int n_ag = in_sizes[2] / 16;
    const int E_s  = in_sizes[3];
    const int E_n  = in_sizes[5];

    char* ws = (char*)d_ws;
    int* cur_s = (int*)ws;  ws += (size_t)n_ag * 4;
    int* cur_n = (int*)ws;  ws += (size_t)n_ag * 4;
    int* csr_s = (int*)ws;  ws += (size_t)E_s * 4;
    int* csr_n = (int*)ws;  ws += (size_t)E_n * 4;
    float* xcat = (float*)ws;   // [n_ag, 512]

    hipMemsetAsync(cur_s, 0, (size_t)n_ag * 8, stream);  // cur_s, cur_n contiguous

    int gE = (E_s + E_n + 255) / 256;
    k_hist<<<gE, 256, 0, stream>>>(seen_dst, E_s, near_dst, E_n, cur_s, cur_n);
    k_scan2<<<2, 1024, 0, stream>>>(cur_s, n_ag, cur_n, n_ag);
    k_scatter<<<gE, 256, 0, stream>>>(seen_src, seen_dst, E_s, near_src, near_dst, E_n,
                                      cur_s, cur_n, csr_s, csr_n);

    // both layers in one persistent launch: 1024 blocks (4/CU), split by work
    const int split = 640;
    k_gat<<<1024, 256, 0, stream>>>(
        x_gt,  cur_s, csr_s, Ws_s, bs_s, Wd_s, bd_s, at_s, Wr_s, br_s,
        x_ubs, cur_n, csr_n, Ws_n, bs_n, Wd_n, bd_n, at_n, Wr_n, br_n,
        x_ag, xcat, n_ag, split);

    k_mlp<<<(n_ag + 15) / 16, 256, 0, stream>>>(xcat, W_a, b_a, (float*)d_out, n_ag);
}

// Round 4
// 485.358 us; speedup vs baseline: 1.0642x; 1.0642x over previous
//
#include <hip/hip_runtime.h>
#include <math.h>

#define NEG 0.2f

typedef short bf16x8 __attribute__((ext_vector_type(8)));
typedef float f32x4  __attribute__((ext_vector_type(4)));

// ---------------------------------------------------------------------------
// CSR build: fused histogram -> single-block scan -> fused scatter
// ---------------------------------------------------------------------------
__global__ void k_hist(const int* __restrict__ dst_s, int Es,
                       const int* __restrict__ dst_n, int En,
                       int* __restrict__ deg_s, int* __restrict__ deg_n) {
    int i = blockIdx.x * 256 + threadIdx.x;
    if (i < Es) atomicAdd(&deg_s[dst_s[i]], 1);
    int j = i - Es;
    if (j >= 0 && j < En) atomicAdd(&deg_n[dst_n[j]], 1);
}

__global__ __launch_bounds__(1024) void k_scan2(int* a, int na, int* b, int nb) {
    int* p = (blockIdx.x == 0) ? a : b;
    int n  = (blockIdx.x == 0) ? na : nb;
    __shared__ int sums[1024];
    int t = threadIdx.x;
    int C = (n + 1023) >> 10;
    int base = t * C;
    int s = 0;
    for (int j = 0; j < C; ++j) { int i = base + j; if (i < n) s += p[i]; }
    sums[t] = s;
    __syncthreads();
    for (int off = 1; off < 1024; off <<= 1) {
        int v = (t >= off) ? sums[t - off] : 0;
        __syncthreads();
        sums[t] += v;
        __syncthreads();
    }
    int run = (t == 0) ? 0 : sums[t - 1];
    for (int j = 0; j < C; ++j) {
        int i = base + j;
        if (i < n) { int v = p[i]; p[i] = run; run += v; }
    }
}

__global__ void k_scatter(const int* __restrict__ src_s, const int* __restrict__ dst_s, int Es,
                          const int* __restrict__ src_n, const int* __restrict__ dst_n, int En,
                          int* __restrict__ cur_s, int* __restrict__ cur_n,
                          int* __restrict__ csr_s, int* __restrict__ csr_n) {
    int i = blockIdx.x * 256 + threadIdx.x;
    if (i < Es) {
        int pos = atomicAdd(&cur_s[dst_s[i]], 1);
        csr_s[pos] = src_s[i];
    }
    int j = i - Es;
    if (j >= 0 && j < En) {
        int pos = atomicAdd(&cur_n[dst_n[j]], 1);
        csr_n[pos] = src_n[j];
    }
}

// ---------------------------------------------------------------------------
// helpers
// ---------------------------------------------------------------------------
static __device__ __forceinline__ void fma4(float4& d, float s, const float4 w) {
    d.x = fmaf(s, w.x, d.x); d.y = fmaf(s, w.y, d.y);
    d.z = fmaf(s, w.z, d.z); d.w = fmaf(s, w.w, d.w);
}
static __device__ __forceinline__ float4 lrelu4(float4 a, float4 b) {
    float4 r; float v;
    v = a.x + b.x; r.x = (v > 0.f) ? v : NEG * v;
    v = a.y + b.y; r.y = (v > 0.f) ? v : NEG * v;
    v = a.z + b.z; r.z = (v > 0.f) ? v : NEG * v;
    v = a.w + b.w; r.w = (v > 0.f) ? v : NEG * v;
    return r;
}
static __device__ __forceinline__ unsigned short f2bf(float f) {   // RNE, finite
    unsigned int x = __float_as_uint(f);
    unsigned int r = (x + 0x7FFFu + ((x >> 16) & 1u)) >> 16;
    return (unsigned short)r;
}

// Sum across each 16-lane DPP row (head h = lanes 16h..16h+15), ~4 VALU ops.
#define DPP_ADD(x, ctrl) \
    ((x) + __int_as_float(__builtin_amdgcn_update_dpp( \
        __float_as_int(x), __float_as_int(x), (ctrl), 0xF, 0xF, true)))
static __device__ __forceinline__ float rowsum16(float v) {
    v = DPP_ADD(v, 0xB1);   // quad_perm xor1
    v = DPP_ADD(v, 0x4E);   // quad_perm xor2
    v = DPP_ADD(v, 0x141);  // row_half_mirror
    v = DPP_ADD(v, 0x140);  // row_mirror
    return v;
}

// ---------------------------------------------------------------------------
// GATv2 layer. One node per wave, 4 contiguous nodes per block (L2-friendly,
// short-lived blocks -- the R1 shape that kept FETCH at 12 MB). No LDS.
// Edge loop processes chunks of 4 edges with a 2-stage pipeline: csr indices
// fetched 2 chunks ahead, feature rows 1 chunk ahead -> ~8 loads in flight
// per wave instead of 2 (the R1..R3 latency bottleneck). DPP head-reduce.
// Output written as bf16 (feeds the MFMA MLP).
// ---------------------------------------------------------------------------
__global__ __launch_bounds__(256, 3) void k_gat(
    const float* __restrict__ x_src, const float* __restrict__ x_ag,
    const int* __restrict__ pfx, const int* __restrict__ csr,
    const float* __restrict__ Ws, const float* __restrict__ bs,
    const float* __restrict__ Wd, const float* __restrict__ bd,
    const float* __restrict__ attn,
    const float* __restrict__ Wr, const float* __restrict__ br,
    unsigned short* __restrict__ xcat, int n_dst, int col_off)
{
    const int t = threadIdx.x;
    const int wave = t >> 6, lane = t & 63;
    const int d0 = lane * 4;
    const int node = blockIdx.x * 4 + wave;
    if (node >= n_dst) return;

    // wave-lifetime constants (coalesced 1KB-row loads, L2/L1-resident)
    float4 ws_r[8];
#pragma unroll
    for (int k = 0; k < 8; ++k) ws_r[k] = *(const float4*)&Ws[k * 256 + d0];
    const float4 bsv = *(const float4*)&bs[d0];
    const float4 atv = *(const float4*)&attn[d0];

    int end   = pfx[node];
    int start = node ? pfx[node - 1] : 0;
    int deg   = end - start;

    // fd = x_ag[node]@Wd + bd, fr = x_ag[node]@Wr + br (4 dims/lane), from L2
    float4 fd = *(const float4*)&bd[d0];
    float4 fr = *(const float4*)&br[d0];
    {
        const float* xr = x_ag + (size_t)node * 16;
        float4 xv[4];
#pragma unroll
        for (int kq = 0; kq < 4; ++kq) xv[kq] = *(const float4*)&xr[kq * 4];
#pragma unroll
        for (int kq = 0; kq < 4; ++kq) {
#pragma unroll
            for (int kk = 0; kk < 4; ++kk) {
                int k = kq * 4 + kk;
                float xk = (kk == 0) ? xv[kq].x : (kk == 1) ? xv[kq].y
                         : (kk == 2) ? xv[kq].z : xv[kq].w;
                fma4(fd, xk, *(const float4*)&Wd[k * 256 + d0]);
                fma4(fr, xk, *(const float4*)&Wr[k * 256 + d0]);
            }
        }
    }

    float m = -INFINITY, l = 0.f;
    float4 acc = make_float4(0.f, 0.f, 0.f, 0.f);

    if (deg > 0) {
        // chunk-4 edge pipeline: idxN = csr values for next chunk,
        // ra/rb = feature rows for current chunk.
        int idxN[4];
        float4 ra[4], rb[4];
        {
            int idx0[4];
#pragma unroll
            for (int j = 0; j < 4; ++j) {
                int e = j < deg ? j : deg - 1;
                idx0[j] = csr[start + e];
            }
#pragma unroll
            for (int j = 0; j < 4; ++j) {
                int e = 4 + j; e = e < deg ? e : deg - 1;
                idxN[j] = csr[start + e];
            }
#pragma unroll
            for (int j = 0; j < 4; ++j) {
                ra[j] = *(const float4*)&x_src[(size_t)idx0[j] * 8];
                rb[j] = *(const float4*)&x_src[(size_t)idx0[j] * 8 + 4];
            }
        }
        for (int base = 0; base < deg; base += 4) {
            // issue next-chunk row loads (addresses ready -> no wait)
            float4 na[4], nb[4];
#pragma unroll
            for (int j = 0; j < 4; ++j) {
                na[j] = *(const float4*)&x_src[(size_t)idxN[j] * 8];
                nb[j] = *(const float4*)&x_src[(size_t)idxN[j] * 8 + 4];
            }
            // issue next-next chunk csr loads
            int idxNN[4];
#pragma unroll
            for (int j = 0; j < 4; ++j) {
                int e = base + 8 + j; e = e < deg ? e : deg - 1;
                idxNN[j] = csr[start + e];
            }
            // compute current chunk (overlaps the loads above)
#pragma unroll
            for (int j = 0; j < 4; ++j) {
                if (base + j < deg) {
                    float4 fs = bsv;
                    fma4(fs, ra[j].x, ws_r[0]);
                    fma4(fs, ra[j].y, ws_r[1]);
                    fma4(fs, ra[j].z, ws_r[2]);
                    fma4(fs, ra[j].w, ws_r[3]);
                    fma4(fs, rb[j].x, ws_r[4]);
                    fma4(fs, rb[j].y, ws_r[5]);
                    fma4(fs, rb[j].z, ws_r[6]);
                    fma4(fs, rb[j].w, ws_r[7]);

                    float4 tt = lrelu4(fs, fd);
                    float sc = tt.x * atv.x;
                    sc = fmaf(tt.y, atv.y, sc);
                    sc = fmaf(tt.z, atv.z, sc);
                    sc = fmaf(tt.w, atv.w, sc);
                    sc = rowsum16(sc);

                    float mn = fmaxf(m, sc);
                    float corr = __expf(m - mn);     // 0 on first edge
                    float p = __expf(sc - mn);
                    l = fmaf(l, corr, p);
                    acc.x = fmaf(acc.x, corr, p * fs.x);
                    acc.y = fmaf(acc.y, corr, p * fs.y);
                    acc.z = fmaf(acc.z, corr, p * fs.z);
                    acc.w = fmaf(acc.w, corr, p * fs.w);
                    m = mn;
                }
            }
            // rotate pipeline
#pragma unroll
            for (int j = 0; j < 4; ++j) {
                idxN[j] = idxNN[j]; ra[j] = na[j]; rb[j] = nb[j];
            }
        }
    }

    float inv = (l > 0.f) ? 1.f / l : 0.f;   // zero in-degree -> rst = 0
    ushort4 o;
    o.x = f2bf(fmaxf(fmaf(acc.x, inv, fr.x), 0.f));
    o.y = f2bf(fmaxf(fmaf(acc.y, inv, fr.y), 0.f));
    o.z = f2bf(fmaxf(fmaf(acc.z, inv, fr.z), 0.f));
    o.w = f2bf(fmaxf(fmaf(acc.w, inv, fr.w), 0.f));
    *(ushort4*)&xcat[(size_t)node * 512 + col_off + d0] = o;
}

// ---------------------------------------------------------------------------
// W_aggr [512][256] f32 -> Wt [256][512] bf16 (transposed, so MFMA B-frags
// read contiguous 16B). Coalesced reads, scattered 2B writes (L2-absorbed).
// ---------------------------------------------------------------------------
__global__ void k_wt(const float* __restrict__ W, unsigned short* __restrict__ Wt) {
    int i = blockIdx.x * 256 + threadIdx.x;   // 512*256 total
    int k = i >> 8, n = i & 255;
    Wt[(size_t)n * 512 + k] = f2bf(W[i]);
}

// ---------------------------------------------------------------------------
// out = relu(X[M,512]bf16 @ W[512,256]bf16 + b) via mfma_f32_16x16x32_bf16.
// Block = 4 waves: rows rbase..rbase+15, wave w covers cols 64w..64w+63
// (4 16x16 acc frags). A/B frags loaded straight from L2 (no LDS):
//   A[m][k]: lane m+16q holds X[rbase+m][k0+8q .. +7]   (16B contiguous)
//   B[k][n]: lane n+16q holds Wt[nbase+n][k0+8q .. +7]  (16B contiguous)
//   D[m][n]: lane: col n=lane&15, row m=q*4+reg
// ---------------------------------------------------------------------------
__global__ __launch_bounds__(256) void k_mlp(
    const unsigned short* __restrict__ X, const unsigned short* __restrict__ Wt,
    const float* __restrict__ b, float* __restrict__ out, int M)
{
    const int t = threadIdx.x;
    const int wave = t >> 6, lane = t & 63;
    const int m16 = lane & 15, q = lane >> 4;
    const int rbase = blockIdx.x * 16;
    const int nbase = wave * 64;

    int rowa = rbase + m16; if (rowa >= M) rowa = M - 1;
    const unsigned short* xp = X + (size_t)rowa * 512 + q * 8;
    const unsigned short* w0 = Wt + (size_t)(nbase + m16) * 512 + q * 8;
    const unsigned short* w1 = w0 + 16 * 512;
    const unsigned short* w2 = w0 + 32 * 512;
    const unsigned short* w3 = w0 + 48 * 512;

    f32x4 ac0 = {0.f, 0.f, 0.f, 0.f}, ac1 = ac0, ac2 = ac0, ac3 = ac0;

#pragma unroll
    for (int k0 = 0; k0 < 512; k0 += 32) {
        bf16x8 a  = *(const bf16x8*)(xp + k0);
        bf16x8 b0 = *(const bf16x8*)(w0 + k0);
        bf16x8 b1 = *(const bf16x8*)(w1 + k0);
        bf16x8 b2 = *(const bf16x8*)(w2 + k0);
        bf16x8 b3 = *(const bf16x8*)(w3 + k0);
        ac0 = __builtin_amdgcn_mfma_f32_16x16x32_bf16(a, b0, ac0, 0, 0, 0);
        ac1 = __builtin_amdgcn_mfma_f32_16x16x32_bf16(a, b1, ac1, 0, 0, 0);
        ac2 = __builtin_amdgcn_mfma_f32_16x16x32_bf16(a, b2, ac2, 0, 0, 0);
        ac3 = __builtin_amdgcn_mfma_f32_16x16x32_bf16(a, b3, ac3, 0, 0, 0);
    }

#define EPI(AC, J) { \
        int coln = nbase + (J) * 16 + m16; \
        float bias = b[coln]; \
        _Pragma("unroll") \
        for (int r = 0; r < 4; ++r) { \
            int orow = rbase + q * 4 + r; \
            if (orow < M) \
                out[(size_t)orow * 256 + coln] = fmaxf(AC[r] + bias, 0.f); \
        } }
    EPI(ac0, 0) EPI(ac1, 1) EPI(ac2, 2) EPI(ac3, 3)
#undef EPI
}

// ---------------------------------------------------------------------------
extern "C" void kernel_launch(void* const* d_in, const int* in_sizes, int n_in,
                              void* d_out, int out_size, void* d_ws, size_t ws_size,
                              hipStream_t stream) {
    const float* x_gt   = (const float*)d_in[0];
    const float* x_ubs  = (const float*)d_in[1];
    const float* x_ag   = (const float*)d_in[2];
    const int* seen_src = (const int*)d_in[3];
    const int* seen_dst = (const int*)d_in[4];
    const int* near_src = (const int*)d_in[5];
    const int* near_dst = (const int*)d_in[6];
    const float* Ws_s = (const float*)d_in[7];  const float* bs_s = (const float*)d_in[8];
    const float* Wd_s = (const float*)d_in[9];  const float* bd_s = (const float*)d_in[10];
    const float* at_s = (const float*)d_in[11];
    const float* Wr_s = (const float*)d_in[12]; const float* br_s = (const float*)d_in[13];
    const float* Ws_n = (const float*)d_in[14]; const float* bs_n = (const float*)d_in[15];
    const float* Wd_n = (const float*)d_in[16]; const float* bd_n = (const float*)d_in[17];
    const float* at_n = (const float*)d_in[18];
    const float* Wr_n = (const float*)d_in[19]; const float* br_n = (const float*)d_in[20];
    const float* W_a  = (const float*)d_in[21]; const float* b_a  = (const float*)d_in[22];

    const int n_ag = in_sizes[2] / 16;
    const int E_s  = in_sizes[3];
    const int E_n  = in_sizes[5];

    char* ws = (char*)d_ws;
    int* cur_s = (int*)ws;              ws += (size_t)n_ag * 4;
    int* cur_n = (int*)ws;              ws += (size_t)n_ag * 4;
    int* csr_s = (int*)ws;              ws += (size_t)E_s * 4;
    int* csr_n = (int*)ws;              ws += (size_t)E_n * 4;
    unsigned short* xcat = (unsigned short*)ws;  ws += (size_t)n_ag * 512 * 2;
    unsigned short* Wt   = (unsigned short*)ws;  // [256][512] bf16

    hipMemsetAsync(cur_s, 0, (size_t)n_ag * 8, stream);  // cur_s, cur_n contiguous

    k_wt<<<512, 256, 0, stream>>>(W_a, Wt);

    int gE = (E_s + E_n + 255) / 256;
    k_hist<<<gE, 256, 0, stream>>>(seen_dst, E_s, near_dst, E_n, cur_s, cur_n);
    k_scan2<<<2, 1024, 0, stream>>>(cur_s, n_ag, cur_n, n_ag);
    k_scatter<<<gE, 256, 0, stream>>>(seen_src, seen_dst, E_s, near_src, near_dst, E_n,
                                      cur_s, cur_n, csr_s, csr_n);

    int gN = (n_ag + 3) / 4;
    k_gat<<<gN, 256, 0, stream>>>(x_gt, x_ag, cur_s, csr_s,
        Ws_s, bs_s, Wd_s, bd_s, at_s, Wr_s, br_s, xcat, n_ag, 0);
    k_gat<<<gN, 256, 0, stream>>>(x_ubs, x_ag, cur_n, csr_n,
        Ws_n, bs_n, Wd_n, bd_n, at_n, Wr_n, br_n, xcat, n_ag, 256);

    k_mlp<<<(n_ag + 15) / 16, 256, 0, stream>>>(xcat, Wt, b_a, (float*)d_out, n_ag);
}

// Round 5
// 451.762 us; speedup vs baseline: 1.1433x; 1.0744x over previous
//
#include <hip/hip_runtime.h>
#include <math.h>

#define NEG 0.2f

typedef short bf16x8 __attribute__((ext_vector_type(8)));
typedef float f32x4  __attribute__((ext_vector_type(4)));

// ---------------------------------------------------------------------------
// helpers
// ---------------------------------------------------------------------------
static __device__ __forceinline__ void fma4(float4& d, float s, const float4 w) {
    d.x = fmaf(s, w.x, d.x); d.y = fmaf(s, w.y, d.y);
    d.z = fmaf(s, w.z, d.z); d.w = fmaf(s, w.w, d.w);
}
static __device__ __forceinline__ float4 lrelu4(float4 a, float4 b) {
    float4 r; float v;
    v = a.x + b.x; r.x = (v > 0.f) ? v : NEG * v;
    v = a.y + b.y; r.y = (v > 0.f) ? v : NEG * v;
    v = a.z + b.z; r.z = (v > 0.f) ? v : NEG * v;
    v = a.w + b.w; r.w = (v > 0.f) ? v : NEG * v;
    return r;
}
static __device__ __forceinline__ unsigned short f2bf(float f) {   // RNE, finite
    unsigned int x = __float_as_uint(f);
    unsigned int r = (x + 0x7FFFu + ((x >> 16) & 1u)) >> 16;
    return (unsigned short)r;
}

// Sum across each 16-lane DPP row (head h = lanes 16h..16h+15), 4 VALU ops.
#define DPP_ADD(x, ctrl) \
    ((x) + __int_as_float(__builtin_amdgcn_update_dpp( \
        __float_as_int(x), __float_as_int(x), (ctrl), 0xF, 0xF, true)))
static __device__ __forceinline__ float rowsum16(float v) {
    v = DPP_ADD(v, 0xB1);   // quad_perm xor1
    v = DPP_ADD(v, 0x4E);   // quad_perm xor2
    v = DPP_ADD(v, 0x141);  // row_half_mirror
    v = DPP_ADD(v, 0x140);  // row_mirror
    return v;
}

// ---------------------------------------------------------------------------
// CSR build: fused histogram + W_aggr transpose -> scan -> scatter
// ---------------------------------------------------------------------------
__global__ void k_hist_wt(const int* __restrict__ dst_s, int Es,
                          const int* __restrict__ dst_n, int En,
                          int* __restrict__ deg_s, int* __restrict__ deg_n,
                          const float* __restrict__ W, unsigned short* __restrict__ Wt) {
    int i = blockIdx.x * 256 + threadIdx.x;
    if (i < Es) atomicAdd(&deg_s[dst_s[i]], 1);
    int j = i - Es;
    if (j >= 0 && j < En) atomicAdd(&deg_n[dst_n[j]], 1);
    if (i < 512 * 256) {                 // W[512][256] f32 -> Wt[256][512] bf16
        int k = i >> 8, n = i & 255;
        Wt[(size_t)n * 512 + k] = f2bf(W[i]);
    }
}

__global__ __launch_bounds__(1024) void k_scan2(int* a, int na, int* b, int nb) {
    int* p = (blockIdx.x == 0) ? a : b;
    int n  = (blockIdx.x == 0) ? na : nb;
    __shared__ int sums[1024];
    int t = threadIdx.x;
    int C = (n + 1023) >> 10;
    int base = t * C;
    int s = 0;
    for (int j = 0; j < C; ++j) { int i = base + j; if (i < n) s += p[i]; }
    sums[t] = s;
    __syncthreads();
    for (int off = 1; off < 1024; off <<= 1) {
        int v = (t >= off) ? sums[t - off] : 0;
        __syncthreads();
        sums[t] += v;
        __syncthreads();
    }
    int run = (t == 0) ? 0 : sums[t - 1];
    for (int j = 0; j < C; ++j) {
        int i = base + j;
        if (i < n) { int v = p[i]; p[i] = run; run += v; }
    }
}

__global__ void k_scatter(const int* __restrict__ src_s, const int* __restrict__ dst_s, int Es,
                          const int* __restrict__ src_n, const int* __restrict__ dst_n, int En,
                          int* __restrict__ cur_s, int* __restrict__ cur_n,
                          int* __restrict__ csr_s, int* __restrict__ csr_n) {
    int i = blockIdx.x * 256 + threadIdx.x;
    if (i < Es) {
        int pos = atomicAdd(&cur_s[dst_s[i]], 1);
        csr_s[pos] = src_s[i];
    }
    int j = i - Es;
    if (j >= 0 && j < En) {
        int pos = atomicAdd(&cur_n[dst_n[j]], 1);
        csr_n[pos] = src_n[j];
    }
}

// ---------------------------------------------------------------------------
// GATv2, both layers fused by contiguous block ranges (block < gNs -> seen).
// One node per wave, 4 contiguous nodes per block, short-lived blocks (the
// R1 shape whose FETCH was 12.7 MB). No LDS.
// Edge loop: chunks of 4 edges, SINGLE row buffer (R4's double buffer made
// the compiler spill to scratch: VGPR_Count 84 vs ~120 live -> 270 MB of
// deterministic spill writes/dispatch). Per chunk: issue all 8 row loads
// together (8 loads in flight = MLP), prefetch next chunk's 4 csr indices
// (4 regs only), then compute. ~105 VGPR -> 4 waves/SIMD, no spill.
// ---------------------------------------------------------------------------
__global__ __launch_bounds__(256, 4) void k_gat(
    const float* __restrict__ xsrc_s, const int* __restrict__ pfx_s, const int* __restrict__ csr_s,
    const float* __restrict__ Ws_s, const float* __restrict__ bs_s,
    const float* __restrict__ Wd_s, const float* __restrict__ bd_s,
    const float* __restrict__ at_s,
    const float* __restrict__ Wr_s, const float* __restrict__ br_s,
    const float* __restrict__ xsrc_n, const int* __restrict__ pfx_n, const int* __restrict__ csr_n,
    const float* __restrict__ Ws_n, const float* __restrict__ bs_n,
    const float* __restrict__ Wd_n, const float* __restrict__ bd_n,
    const float* __restrict__ at_n,
    const float* __restrict__ Wr_n, const float* __restrict__ br_n,
    const float* __restrict__ x_ag,
    unsigned short* __restrict__ xcat, int n_dst, int gNs)
{
    const bool seen = (int)blockIdx.x < gNs;
    const float* x_src = seen ? xsrc_s : xsrc_n;
    const int*   pfx   = seen ? pfx_s  : pfx_n;
    const int*   csr   = seen ? csr_s  : csr_n;
    const float* Ws    = seen ? Ws_s   : Ws_n;
    const float* bs    = seen ? bs_s   : bs_n;
    const float* Wd    = seen ? Wd_s   : Wd_n;
    const float* bd    = seen ? bd_s   : bd_n;
    const float* at    = seen ? at_s   : at_n;
    const float* Wr    = seen ? Wr_s   : Wr_n;
    const float* br    = seen ? br_s   : br_n;
    const int col = seen ? 0 : 256;
    const int blk = seen ? (int)blockIdx.x : (int)blockIdx.x - gNs;

    const int t = threadIdx.x;
    const int wave = t >> 6, lane = t & 63;
    const int d0 = lane * 4;
    const int node = blk * 4 + wave;
    if (node >= n_dst) return;

    // wave-lifetime constants (coalesced 1KB-row loads, L1/L2-resident)
    float4 ws_r[8];
#pragma unroll
    for (int k = 0; k < 8; ++k) ws_r[k] = *(const float4*)&Ws[k * 256 + d0];
    const float4 bsv = *(const float4*)&bs[d0];
    const float4 atv = *(const float4*)&at[d0];

    int end   = pfx[node];
    int start = node ? pfx[node - 1] : 0;
    int deg   = end - start;

    // fd = x_ag[node]@Wd + bd, fr = x_ag[node]@Wr + br (4 dims/lane), from L2
    float4 fd = *(const float4*)&bd[d0];
    float4 fr = *(const float4*)&br[d0];
    {
        const float* xr = x_ag + (size_t)node * 16;
        float4 xv[4];
#pragma unroll
        for (int kq = 0; kq < 4; ++kq) xv[kq] = *(const float4*)&xr[kq * 4];
#pragma unroll
        for (int kq = 0; kq < 4; ++kq) {
#pragma unroll
            for (int kk = 0; kk < 4; ++kk) {
                int k = kq * 4 + kk;
                float xk = (kk == 0) ? xv[kq].x : (kk == 1) ? xv[kq].y
                         : (kk == 2) ? xv[kq].z : xv[kq].w;
                fma4(fd, xk, *(const float4*)&Wd[k * 256 + d0]);
                fma4(fr, xk, *(const float4*)&Wr[k * 256 + d0]);
            }
        }
    }

    float m = -INFINITY, l = 0.f;
    float4 acc = make_float4(0.f, 0.f, 0.f, 0.f);

    if (deg > 0) {
        int idxC[4];
#pragma unroll
        for (int j = 0; j < 4; ++j) {
            int e = j < deg ? j : deg - 1;
            idxC[j] = csr[start + e];
        }
        for (int base = 0; base < deg; base += 4) {
            // issue all 8 row loads for this chunk (8 in flight)
            float4 ra[4], rb[4];
#pragma unroll
            for (int j = 0; j < 4; ++j) {
                ra[j] = *(const float4*)&x_src[(size_t)idxC[j] * 8];
                rb[j] = *(const float4*)&x_src[(size_t)idxC[j] * 8 + 4];
            }
            // prefetch next chunk's indices (4 regs; overlaps the row waits)
            int idxN[4];
#pragma unroll
            for (int j = 0; j < 4; ++j) {
                int e = base + 4 + j; e = e < deg ? e : deg - 1;
                idxN[j] = csr[start + e];
            }
            // compute the 4 edges
#pragma unroll
            for (int j = 0; j < 4; ++j) {
                if (base + j < deg) {
                    float4 fs = bsv;
                    fma4(fs, ra[j].x, ws_r[0]);
                    fma4(fs, ra[j].y, ws_r[1]);
                    fma4(fs, ra[j].z, ws_r[2]);
                    fma4(fs, ra[j].w, ws_r[3]);
                    fma4(fs, rb[j].x, ws_r[4]);
                    fma4(fs, rb[j].y, ws_r[5]);
                    fma4(fs, rb[j].z, ws_r[6]);
                    fma4(fs, rb[j].w, ws_r[7]);

                    float4 tt = lrelu4(fs, fd);
                    float sc = tt.x * atv.x;
                    sc = fmaf(tt.y, atv.y, sc);
                    sc = fmaf(tt.z, atv.z, sc);
                    sc = fmaf(tt.w, atv.w, sc);
                    sc = rowsum16(sc);

                    float mn = fmaxf(m, sc);
                    float corr = __expf(m - mn);     // 0 on first edge
                    float p = __expf(sc - mn);
                    l = fmaf(l, corr, p);
                    acc.x = fmaf(acc.x, corr, p * fs.x);
                    acc.y = fmaf(acc.y, corr, p * fs.y);
                    acc.z = fmaf(acc.z, corr, p * fs.z);
                    acc.w = fmaf(acc.w, corr, p * fs.w);
                    m = mn;
                }
            }
#pragma unroll
            for (int j = 0; j < 4; ++j) idxC[j] = idxN[j];
        }
    }

    float inv = (l > 0.f) ? 1.f / l : 0.f;   // zero in-degree -> rst = 0
    ushort4 o;
    o.x = f2bf(fmaxf(fmaf(acc.x, inv, fr.x), 0.f));
    o.y = f2bf(fmaxf(fmaf(acc.y, inv, fr.y), 0.f));
    o.z = f2bf(fmaxf(fmaf(acc.z, inv, fr.z), 0.f));
    o.w = f2bf(fmaxf(fmaf(acc.w, inv, fr.w), 0.f));
    *(ushort4*)&xcat[(size_t)node * 512 + col + d0] = o;
}

// ---------------------------------------------------------------------------
// out = relu(X[M,512]bf16 @ W[512,256]bf16 + b) via mfma_f32_16x16x32_bf16.
// Block = 4 waves: rows rbase..rbase+15, wave w covers cols 64w..64w+63.
// A/B frags straight from L2 (no LDS). D: col n=lane&15, row m=q*4+reg.
// ---------------------------------------------------------------------------
__global__ __launch_bounds__(256) void k_mlp(
    const unsigned short* __restrict__ X, const unsigned short* __restrict__ Wt,
    const float* __restrict__ b, float* __restrict__ out, int M)
{
    const int t = threadIdx.x;
    const int wave = t >> 6, lane = t & 63;
    const int m16 = lane & 15, q = lane >> 4;
    const int rbase = blockIdx.x * 16;
    const int nbase = wave * 64;

    int rowa = rbase + m16; if (rowa >= M) rowa = M - 1;
    const unsigned short* xp = X + (size_t)rowa * 512 + q * 8;
    const unsigned short* w0 = Wt + (size_t)(nbase + m16) * 512 + q * 8;
    const unsigned short* w1 = w0 + 16 * 512;
    const unsigned short* w2 = w0 + 32 * 512;
    const unsigned short* w3 = w0 + 48 * 512;

    f32x4 ac0 = {0.f, 0.f, 0.f, 0.f}, ac1 = ac0, ac2 = ac0, ac3 = ac0;

#pragma unroll
    for (int k0 = 0; k0 < 512; k0 += 32) {
        bf16x8 a  = *(const bf16x8*)(xp + k0);
        bf16x8 b0 = *(const bf16x8*)(w0 + k0);
        bf16x8 b1 = *(const bf16x8*)(w1 + k0);
        bf16x8 b2 = *(const bf16x8*)(w2 + k0);
        bf16x8 b3 = *(const bf16x8*)(w3 + k0);
        ac0 = __builtin_amdgcn_mfma_f32_16x16x32_bf16(a, b0, ac0, 0, 0, 0);
        ac1 = __builtin_amdgcn_mfma_f32_16x16x32_bf16(a, b1, ac1, 0, 0, 0);
        ac2 = __builtin_amdgcn_mfma_f32_16x16x32_bf16(a, b2, ac2, 0, 0, 0);
        ac3 = __builtin_amdgcn_mfma_f32_16x16x32_bf16(a, b3, ac3, 0, 0, 0);
    }

#define EPI(AC, J) { \
        int coln = nbase + (J) * 16 + m16; \
        float bias = b[coln]; \
        _Pragma("unroll") \
        for (int r = 0; r < 4; ++r) { \
            int orow = rbase + q * 4 + r; \
            if (orow < M) \
                out[(size_t)orow * 256 + coln] = fmaxf(AC[r] + bias, 0.f); \
        } }
    EPI(ac0, 0) EPI(ac1, 1) EPI(ac2, 2) EPI(ac3, 3)
#undef EPI
}

// ---------------------------------------------------------------------------
extern "C" void kernel_launch(void* const* d_in, const int* in_sizes, int n_in,
                              void* d_out, int out_size, void* d_ws, size_t ws_size,
                              hipStream_t stream) {
    const float* x_gt   = (const float*)d_in[0];
    const float* x_ubs  = (const float*)d_in[1];
    const float* x_ag   = (const float*)d_in[2];
    const int* seen_src = (const int*)d_in[3];
    const int* seen_dst = (const int*)d_in[4];
    const int* near_src = (const int*)d_in[5];
    const int* near_dst = (const int*)d_in[6];
    const float* Ws_s = (const float*)d_in[7];  const float* bs_s = (const float*)d_in[8];
    const float* Wd_s = (const float*)d_in[9];  const float* bd_s = (const float*)d_in[10];
    const float* at_s = (const float*)d_in[11];
    const float* Wr_s = (const float*)d_in[12]; const float* br_s = (const float*)d_in[13];
    const float* Ws_n = (const float*)d_in[14]; const float* bs_n = (const float*)d_in[15];
    const float* Wd_n = (const float*)d_in[16]; const float* bd_n = (const float*)d_in[17];
    const float* at_n = (const float*)d_in[18];
    const float* Wr_n = (const float*)d_in[19]; const float* br_n = (const float*)d_in[20];
    const float* W_a  = (const float*)d_in[21]; const float* b_a  = (const float*)d_in[22];

    const int n_ag = in_sizes[2] / 16;
    const int E_s  = in_sizes[3];
    const int E_n  = in_sizes[5];

    char* ws = (char*)d_ws;
    int* cur_s = (int*)ws;              ws += (size_t)n_ag * 4;
    int* cur_n = (int*)ws;              ws += (size_t)n_ag * 4;
    int* csr_s = (int*)ws;              ws += (size_t)E_s * 4;
    int* csr_n = (int*)ws;              ws += (size_t)E_n * 4;
    unsigned short* xcat = (unsigned short*)ws;  ws += (size_t)n_ag * 512 * 2;
    unsigned short* Wt   = (unsigned short*)ws;  // [256][512] bf16

    hipMemsetAsync(cur_s, 0, (size_t)n_ag * 8, stream);  // cur_s, cur_n contiguous

    int gE = (E_s + E_n + 255) / 256;
    k_hist_wt<<<gE, 256, 0, stream>>>(seen_dst, E_s, near_dst, E_n, cur_s, cur_n, W_a, Wt);
    k_scan2<<<2, 1024, 0, stream>>>(cur_s, n_ag, cur_n, n_ag);
    k_scatter<<<gE, 256, 0, stream>>>(seen_src, seen_dst, E_s, near_src, near_dst, E_n,
                                      cur_s, cur_n, csr_s, csr_n);

    int gN = (n_ag + 3) / 4;
    k_gat<<<2 * gN, 256, 0, stream>>>(
        x_gt,  cur_s, csr_s, Ws_s, bs_s, Wd_s, bd_s, at_s, Wr_s, br_s,
        x_ubs, cur_n, csr_n, Ws_n, bs_n, Wd_n, bd_n, at_n, Wr_n, br_n,
        x_ag, xcat, n_ag, gN);

    k_mlp<<<(n_ag + 15) / 16, 256, 0, stream>>>(xcat, Wt, b_a, (float*)d_out, n_ag);
}

// Round 6
// 353.340 us; speedup vs baseline: 1.4618x; 1.2785x over previous
//
#include <hip/hip_runtime.h>
#include <math.h>

#define NEG 0.2f

typedef short bf16x8 __attribute__((ext_vector_type(8)));
typedef float f32x4  __attribute__((ext_vector_type(4)));

// ---------------------------------------------------------------------------
// helpers
// ---------------------------------------------------------------------------
static __device__ __forceinline__ void fma4(float4& d, float s, const float4 w) {
    d.x = fmaf(s, w.x, d.x); d.y = fmaf(s, w.y, d.y);
    d.z = fmaf(s, w.z, d.z); d.w = fmaf(s, w.w, d.w);
}
static __device__ __forceinline__ float4 lrelu4(float4 a, float4 b) {
    float4 r; float v;
    v = a.x + b.x; r.x = (v > 0.f) ? v : NEG * v;
    v = a.y + b.y; r.y = (v > 0.f) ? v : NEG * v;
    v = a.z + b.z; r.z = (v > 0.f) ? v : NEG * v;
    v = a.w + b.w; r.w = (v > 0.f) ? v : NEG * v;
    return r;
}
static __device__ __forceinline__ unsigned short f2bf(float f) {   // RNE, finite
    unsigned int x = __float_as_uint(f);
    unsigned int r = (x + 0x7FFFu + ((x >> 16) & 1u)) >> 16;
    return (unsigned short)r;
}
// broadcast one lane's float to all lanes (immediate lane idx -> SGPR)
static __device__ __forceinline__ float rlane(float v, int l) {
    return __int_as_float(__builtin_amdgcn_readlane(__float_as_int(v), l));
}

// Sum across each 16-lane DPP row (head h = lanes 16h..16h+15), 4 VALU ops.
#define DPP_ADD(x, ctrl) \
    ((x) + __int_as_float(__builtin_amdgcn_update_dpp( \
        __float_as_int(x), __float_as_int(x), (ctrl), 0xF, 0xF, true)))
static __device__ __forceinline__ float rowsum16(float v) {
    v = DPP_ADD(v, 0xB1);   // quad_perm xor1
    v = DPP_ADD(v, 0x4E);   // quad_perm xor2
    v = DPP_ADD(v, 0x141);  // row_half_mirror
    v = DPP_ADD(v, 0x140);  // row_mirror
    return v;
}

// ---------------------------------------------------------------------------
// CSR build: fused histogram + W_aggr transpose -> scan -> scatter
// ---------------------------------------------------------------------------
__global__ void k_hist_wt(const int* __restrict__ dst_s, int Es,
                          const int* __restrict__ dst_n, int En,
                          int* __restrict__ deg_s, int* __restrict__ deg_n,
                          const float* __restrict__ W, unsigned short* __restrict__ Wt) {
    int i = blockIdx.x * 256 + threadIdx.x;
    if (i < Es) atomicAdd(&deg_s[dst_s[i]], 1);
    int j = i - Es;
    if (j >= 0 && j < En) atomicAdd(&deg_n[dst_n[j]], 1);
    if (i < 512 * 256) {                 // W[512][256] f32 -> Wt[256][512] bf16
        int k = i >> 8, n = i & 255;
        Wt[(size_t)n * 512 + k] = f2bf(W[i]);
    }
}

__global__ __launch_bounds__(1024) void k_scan2(int* a, int na, int* b, int nb) {
    int* p = (blockIdx.x == 0) ? a : b;
    int n  = (blockIdx.x == 0) ? na : nb;
    __shared__ int sums[1024];
    int t = threadIdx.x;
    int C = (n + 1023) >> 10;
    int base = t * C;
    int s = 0;
    for (int j = 0; j < C; ++j) { int i = base + j; if (i < n) s += p[i]; }
    sums[t] = s;
    __syncthreads();
    for (int off = 1; off < 1024; off <<= 1) {
        int v = (t >= off) ? sums[t - off] : 0;
        __syncthreads();
        sums[t] += v;
        __syncthreads();
    }
    int run = (t == 0) ? 0 : sums[t - 1];
    for (int j = 0; j < C; ++j) {
        int i = base + j;
        if (i < n) { int v = p[i]; p[i] = run; run += v; }
    }
}

__global__ void k_scatter(const int* __restrict__ src_s, const int* __restrict__ dst_s, int Es,
                          const int* __restrict__ src_n, const int* __restrict__ dst_n, int En,
                          int* __restrict__ cur_s, int* __restrict__ cur_n,
                          int* __restrict__ csr_s, int* __restrict__ csr_n) {
    int i = blockIdx.x * 256 + threadIdx.x;
    if (i < Es) {
        int pos = atomicAdd(&cur_s[dst_s[i]], 1);
        csr_s[pos] = src_s[i];
    }
    int j = i - Es;
    if (j >= 0 && j < En) {
        int pos = atomicAdd(&cur_n[dst_n[j]], 1);
        csr_n[pos] = src_n[j];
    }
}

// ---------------------------------------------------------------------------
// GATv2, both layers fused by contiguous block ranges (block < gNs -> seen).
// One node per wave, 4 contiguous nodes per block, short-lived blocks.
//
// Edge loop: chunks of 8 edges. The LANES are the row buffer: lane L loads
// word (L&7) of row csr[base+(L>>3)] -- ONE global_load_dword puts 8 edge
// rows in flight (the MLP R1 lacked), and double-buffering the chunk costs
// 1 VGPR (vs R4/R5's 64-reg row arrays, which the compiler spilled to
// scratch: 270..500 MB WRITE_SIZE). Row words are consumed via v_readlane
// (immediate lane index -> SGPR operand FMAs). No launch_bounds second arg
// (empirically forced the spills). ~85 VGPR expected.
// ---------------------------------------------------------------------------
__global__ __launch_bounds__(256) void k_gat(
    const float* __restrict__ xsrc_s, const int* __restrict__ pfx_s, const int* __restrict__ csr_s,
    const float* __restrict__ Ws_s, const float* __restrict__ bs_s,
    const float* __restrict__ Wd_s, const float* __restrict__ bd_s,
    const float* __restrict__ at_s,
    const float* __restrict__ Wr_s, const float* __restrict__ br_s,
    const float* __restrict__ xsrc_n, const int* __restrict__ pfx_n, const int* __restrict__ csr_n,
    const float* __restrict__ Ws_n, const float* __restrict__ bs_n,
    const float* __restrict__ Wd_n, const float* __restrict__ bd_n,
    const float* __restrict__ at_n,
    const float* __restrict__ Wr_n, const float* __restrict__ br_n,
    const float* __restrict__ x_ag,
    unsigned short* __restrict__ xcat, int n_dst, int gNs)
{
    const bool seen = (int)blockIdx.x < gNs;
    const float* x_src = seen ? xsrc_s : xsrc_n;
    const int*   pfx   = seen ? pfx_s  : pfx_n;
    const int*   csr   = seen ? csr_s  : csr_n;
    const float* Ws    = seen ? Ws_s   : Ws_n;
    const float* bs    = seen ? bs_s   : bs_n;
    const float* Wd    = seen ? Wd_s   : Wd_n;
    const float* bd    = seen ? bd_s   : bd_n;
    const float* at    = seen ? at_s   : at_n;
    const float* Wr    = seen ? Wr_s   : Wr_n;
    const float* br    = seen ? br_s   : br_n;
    const int col = seen ? 0 : 256;
    const int blk = seen ? (int)blockIdx.x : (int)blockIdx.x - gNs;

    const int t = threadIdx.x;
    const int wave = t >> 6, lane = t & 63;
    const int d0 = lane * 4;
    const int node = blk * 4 + wave;
    if (node >= n_dst) return;

    // wave-lifetime constants (coalesced 1KB-row loads, L1/L2-resident)
    float4 ws_r[8];
#pragma unroll
    for (int k = 0; k < 8; ++k) ws_r[k] = *(const float4*)&Ws[k * 256 + d0];
    const float4 bsv = *(const float4*)&bs[d0];
    const float4 atv = *(const float4*)&at[d0];

    int end   = pfx[node];
    int start = node ? pfx[node - 1] : 0;
    int deg   = end - start;

    // fd = x_ag[node]@Wd + bd, fr = x_ag[node]@Wr + br (4 dims/lane), from L2
    float4 fd = *(const float4*)&bd[d0];
    float4 fr = *(const float4*)&br[d0];
    {
        const float* xr = x_ag + (size_t)node * 16;
        float4 xv[4];
#pragma unroll
        for (int kq = 0; kq < 4; ++kq) xv[kq] = *(const float4*)&xr[kq * 4];
#pragma unroll
        for (int kq = 0; kq < 4; ++kq) {
#pragma unroll
            for (int kk = 0; kk < 4; ++kk) {
                int k = kq * 4 + kk;
                float xk = (kk == 0) ? xv[kq].x : (kk == 1) ? xv[kq].y
                         : (kk == 2) ? xv[kq].z : xv[kq].w;
                fma4(fd, xk, *(const float4*)&Wd[k * 256 + d0]);
                fma4(fr, xk, *(const float4*)&Wr[k * 256 + d0]);
            }
        }
    }

    float m = -INFINITY, l = 0.f;
    float4 acc = make_float4(0.f, 0.f, 0.f, 0.f);

    if (deg > 0) {
        const int g  = lane >> 3;   // edge slot 0..7 within chunk
        const int w8 = lane & 7;    // word within the 8-float row

        int e0 = (g < deg) ? g : deg - 1;
        int i0 = csr[start + e0];
        float r0 = x_src[(size_t)i0 * 8 + w8];        // 8 rows in flight
        int e1 = (8 + g < deg) ? 8 + g : deg - 1;
        int i1 = csr[start + e1];

        for (int base = 0; base < deg; base += 8) {
            // prefetch next chunk's rows (1 VGPR) and next-next indices
            float r1 = x_src[(size_t)i1 * 8 + w8];
            int e2 = base + 16 + g; e2 = (e2 < deg) ? e2 : deg - 1;
            int i2 = csr[start + e2];

            // compute the 8 edges of this chunk from r0 via readlane
#pragma unroll
            for (int j = 0; j < 8; ++j) {
                if (base + j < deg) {
                    float x0 = rlane(r0, j * 8 + 0);
                    float x1 = rlane(r0, j * 8 + 1);
                    float x2 = rlane(r0, j * 8 + 2);
                    float x3 = rlane(r0, j * 8 + 3);
                    float x4 = rlane(r0, j * 8 + 4);
                    float x5 = rlane(r0, j * 8 + 5);
                    float x6 = rlane(r0, j * 8 + 6);
                    float x7 = rlane(r0, j * 8 + 7);

                    float4 fs = bsv;
                    fma4(fs, x0, ws_r[0]);
                    fma4(fs, x1, ws_r[1]);
                    fma4(fs, x2, ws_r[2]);
                    fma4(fs, x3, ws_r[3]);
                    fma4(fs, x4, ws_r[4]);
                    fma4(fs, x5, ws_r[5]);
                    fma4(fs, x6, ws_r[6]);
                    fma4(fs, x7, ws_r[7]);

                    float4 tt = lrelu4(fs, fd);
                    float sc = tt.x * atv.x;
                    sc = fmaf(tt.y, atv.y, sc);
                    sc = fmaf(tt.z, atv.z, sc);
                    sc = fmaf(tt.w, atv.w, sc);
                    sc = rowsum16(sc);

                    float mn = fmaxf(m, sc);
                    float corr = __expf(m - mn);     // 0 on first edge
                    float p = __expf(sc - mn);
                    l = fmaf(l, corr, p);
                    acc.x = fmaf(acc.x, corr, p * fs.x);
                    acc.y = fmaf(acc.y, corr, p * fs.y);
                    acc.z = fmaf(acc.z, corr, p * fs.z);
                    acc.w = fmaf(acc.w, corr, p * fs.w);
                    m = mn;
                }
            }
            r0 = r1; i1 = i2;
        }
    }

    float inv = (l > 0.f) ? 1.f / l : 0.f;   // zero in-degree -> rst = 0
    ushort4 o;
    o.x = f2bf(fmaxf(fmaf(acc.x, inv, fr.x), 0.f));
    o.y = f2bf(fmaxf(fmaf(acc.y, inv, fr.y), 0.f));
    o.z = f2bf(fmaxf(fmaf(acc.z, inv, fr.z), 0.f));
    o.w = f2bf(fmaxf(fmaf(acc.w, inv, fr.w), 0.f));
    *(ushort4*)&xcat[(size_t)node * 512 + col + d0] = o;
}

// ---------------------------------------------------------------------------
// out = relu(X[M,512]bf16 @ W[512,256]bf16 + b) via mfma_f32_16x16x32_bf16.
// Block = 4 waves: rows rbase..rbase+15, wave w covers cols 64w..64w+63.
// A/B frags straight from L2 (no LDS). D: col n=lane&15, row m=q*4+reg.
// ---------------------------------------------------------------------------
__global__ __launch_bounds__(256) void k_mlp(
    const unsigned short* __restrict__ X, const unsigned short* __restrict__ Wt,
    const float* __restrict__ b, float* __restrict__ out, int M)
{
    const int t = threadIdx.x;
    const int wave = t >> 6, lane = t & 63;
    const int m16 = lane & 15, q = lane >> 4;
    const int rbase = blockIdx.x * 16;
    const int nbase = wave * 64;

    int rowa = rbase + m16; if (rowa >= M) rowa = M - 1;
    const unsigned short* xp = X + (size_t)rowa * 512 + q * 8;
    const unsigned short* w0 = Wt + (size_t)(nbase + m16) * 512 + q * 8;
    const unsigned short* w1 = w0 + 16 * 512;
    const unsigned short* w2 = w0 + 32 * 512;
    const unsigned short* w3 = w0 + 48 * 512;

    f32x4 ac0 = {0.f, 0.f, 0.f, 0.f}, ac1 = ac0, ac2 = ac0, ac3 = ac0;

#pragma unroll
    for (int k0 = 0; k0 < 512; k0 += 32) {
        bf16x8 a  = *(const bf16x8*)(xp + k0);
        bf16x8 b0 = *(const bf16x8*)(w0 + k0);
        bf16x8 b1 = *(const bf16x8*)(w1 + k0);
        bf16x8 b2 = *(const bf16x8*)(w2 + k0);
        bf16x8 b3 = *(const bf16x8*)(w3 + k0);
        ac0 = __builtin_amdgcn_mfma_f32_16x16x32_bf16(a, b0, ac0, 0, 0, 0);
        ac1 = __builtin_amdgcn_mfma_f32_16x16x32_bf16(a, b1, ac1, 0, 0, 0);
        ac2 = __builtin_amdgcn_mfma_f32_16x16x32_bf16(a, b2, ac2, 0, 0, 0);
        ac3 = __builtin_amdgcn_mfma_f32_16x16x32_bf16(a, b3, ac3, 0, 0, 0);
    }

#define EPI(AC, J) { \
        int coln = nbase + (J) * 16 + m16; \
        float bias = b[coln]; \
        _Pragma("unroll") \
        for (int r = 0; r < 4; ++r) { \
            int orow = rbase + q * 4 + r; \
            if (orow < M) \
                out[(size_t)orow * 256 + coln] = fmaxf(AC[r] + bias, 0.f); \
        } }
    EPI(ac0, 0) EPI(ac1, 1) EPI(ac2, 2) EPI(ac3, 3)
#undef EPI
}

// ---------------------------------------------------------------------------
extern "C" void kernel_launch(void* const* d_in, const int* in_sizes, int n_in,
                              void* d_out, int out_size, void* d_ws, size_t ws_size,
                              hipStream_t stream) {
    const float* x_gt   = (const float*)d_in[0];
    const float* x_ubs  = (const float*)d_in[1];
    const float* x_ag   = (const float*)d_in[2];
    const int* seen_src = (const int*)d_in[3];
    const int* seen_dst = (const int*)d_in[4];
    const int* near_src = (const int*)d_in[5];
    const int* near_dst = (const int*)d_in[6];
    const float* Ws_s = (const float*)d_in[7];  const float* bs_s = (const float*)d_in[8];
    const float* Wd_s = (const float*)d_in[9];  const float* bd_s = (const float*)d_in[10];
    const float* at_s = (const float*)d_in[11];
    const float* Wr_s = (const float*)d_in[12]; const float* br_s = (const float*)d_in[13];
    const float* Ws_n = (const float*)d_in[14]; const float* bs_n = (const float*)d_in[15];
    const float* Wd_n = (const float*)d_in[16]; const float* bd_n = (const float*)d_in[17];
    const float* at_n = (const float*)d_in[18];
    const float* Wr_n = (const float*)d_in[19]; const float* br_n = (const float*)d_in[20];
    const float* W_a  = (const float*)d_in[21]; const float* b_a  = (const float*)d_in[22];

    const int n_ag = in_sizes[2] / 16;
    const int E_s  = in_sizes[3];
    const int E_n  = in_sizes[5];

    char* ws = (char*)d_ws;
    int* cur_s = (int*)ws;              ws += (size_t)n_ag * 4;
    int* cur_n = (int*)ws;              ws += (size_t)n_ag * 4;
    int* csr_s = (int*)ws;              ws += (size_t)E_s * 4;
    int* csr_n = (int*)ws;              ws += (size_t)E_n * 4;
    unsigned short* xcat = (unsigned short*)ws;  ws += (size_t)n_ag * 512 * 2;
    unsigned short* Wt   = (unsigned short*)ws;  // [256][512] bf16

    hipMemsetAsync(cur_s, 0, (size_t)n_ag * 8, stream);  // cur_s, cur_n contiguous

    int gE = (E_s + E_n + 255) / 256;
    k_hist_wt<<<gE, 256, 0, stream>>>(seen_dst, E_s, near_dst, E_n, cur_s, cur_n, W_a, Wt);
    k_scan2<<<2, 1024, 0, stream>>>(cur_s, n_ag, cur_n, n_ag);
    k_scatter<<<gE, 256, 0, stream>>>(seen_src, seen_dst, E_s, near_src, near_dst, E_n,
                                      cur_s, cur_n, csr_s, csr_n);

    int gN = (n_ag + 3) / 4;
    k_gat<<<2 * gN, 256, 0, stream>>>(
        x_gt,  cur_s, csr_s, Ws_s, bs_s, Wd_s, bd_s, at_s, Wr_s, br_s,
        x_ubs, cur_n, csr_n, Ws_n, bs_n, Wd_n, bd_n, at_n, Wr_n, br_n,
        x_ag, xcat, n_ag, gN);

    k_mlp<<<(n_ag + 15) / 16, 256, 0, stream>>>(xcat, Wt, b_a, (float*)d_out, n_ag);
}